// Round 13
// baseline (226.574 us; speedup 1.0000x reference)
//
#include <hip/hip_runtime.h>

constexpr int NN  = 100000;   // nodes
constexpr int NE  = 1600000;  // edges
constexpr int NE4 = NE / 4;   // edge quads
constexpr int HID = 32;
constexpr int NPB = 128;                      // nodes per bucket (= 1<<7)
constexpr int NBIN = (NN + NPB - 1) / NPB;    // 782 buckets
constexpr int NB  = (NN + 255) / 256;         // 391

constexpr int NPART = 8;                      // XCD partitions
constexpr int PPB   = (NBIN + NPART - 1) / NPART;  // 98 buckets per partition
constexpr int NCHUNK = 120;                   // edge chunks (grid = 960)
constexpr int CAP   = 16;                     // queue entries = 64B flush chunk
constexpr int QS    = CAP + 1;                // padded stride (bank spread)
constexpr int BSTRIDE = 2048;                 // extra csr slots per bucket (row padding)

// ---------------- build: bucket scatter + per-bucket counting sort ----------------

__global__ __launch_bounds__(256) void k_binhist(const int* __restrict__ ei,
                                                 int* __restrict__ bincnt) {
  __shared__ int lh[NBIN];
  int t = threadIdx.x;
  for (int b = t; b < NBIN; b += 256) lh[b] = 0;
  __syncthreads();
  const int4* d4 = (const int4*)(ei + NE);
  for (int q = blockIdx.x * 256 + t; q < NE4; q += gridDim.x * 256) {
    int4 v = d4[q];
    atomicAdd(&lh[v.x >> 7], 1);
    atomicAdd(&lh[v.y >> 7], 1);
    atomicAdd(&lh[v.z >> 7], 1);
    atomicAdd(&lh[v.w >> 7], 1);
  }
  __syncthreads();
  for (int b = t; b < NBIN; b += 256) {
    int v = lh[b];
    if (v) atomicAdd(&bincnt[b], v);
  }
}

__global__ __launch_bounds__(1024) void k_binscan(const int* __restrict__ bincnt,
                                                  int* __restrict__ binptr,
                                                  int* __restrict__ cursor) {
  __shared__ int s[1024];
  int t = threadIdx.x;
  int v = (t < NBIN) ? bincnt[t] : 0;
  s[t] = v;
  __syncthreads();
#pragma unroll
  for (int off = 1; off < 1024; off <<= 1) {
    int add = (t >= off) ? s[t - off] : 0;
    __syncthreads();
    s[t] += add;
    __syncthreads();
  }
  if (t < NBIN) {
    int ex = s[t] - v;
    binptr[t] = ex;
    cursor[t] = ex;
  }
  if (t == NBIN - 1) binptr[NBIN] = s[t];
}

// LDS write-combining scatter, 4-edge coarsened; src loaded as int4
__global__ __launch_bounds__(256) void k_wcscatter(const int* __restrict__ ei,
                                                   int* __restrict__ cursor,
                                                   int* __restrict__ be) {
  __shared__ int q[PPB * QS];
  __shared__ int qn[PPB];
  int t = threadIdx.x;
  int part  = blockIdx.x & (NPART - 1);
  int chunk = blockIdx.x >> 3;
  int b0  = part * PPB;
  int bHi = min(b0 + PPB, NBIN);
  int nb  = bHi - b0;
  for (int b = t; b < nb; b += 256) qn[b] = 0;
  int q0 = (int)((long long)NE4 * chunk / NCHUNK);
  int q1 = (int)((long long)NE4 * (chunk + 1) / NCHUNK);
  const int4* d4 = (const int4*)(ei + NE);
  const int4* s4 = (const int4*)ei;
  __syncthreads();
  for (int qbase = q0; qbase < q1; qbase += 256) {
    int qi = qbase + t;
    int4 dv = make_int4(-1, -1, -1, -1);
    int4 sv = make_int4(0, 0, 0, 0);
    if (qi < q1) { dv = d4[qi]; sv = s4[qi]; }
    int val0 = 0, val1 = 0, val2 = 0, val3 = 0;
    int lb0 = 0, lb1 = 0, lb2 = 0, lb3 = 0;
    unsigned pend = 0;
    {
      int bkt = dv.x >> 7;
      if (dv.x >= 0 && bkt >= b0 && bkt < bHi) {
        val0 = sv.x | ((dv.x & (NPB - 1)) << 17);
        lb0 = bkt - b0;
        int slot = atomicAdd(&qn[lb0], 1);
        if (slot < CAP) q[lb0 * QS + slot] = val0; else pend |= 1u;
      }
    }
    {
      int bkt = dv.y >> 7;
      if (dv.y >= 0 && bkt >= b0 && bkt < bHi) {
        val1 = sv.y | ((dv.y & (NPB - 1)) << 17);
        lb1 = bkt - b0;
        int slot = atomicAdd(&qn[lb1], 1);
        if (slot < CAP) q[lb1 * QS + slot] = val1; else pend |= 2u;
      }
    }
    {
      int bkt = dv.z >> 7;
      if (dv.z >= 0 && bkt >= b0 && bkt < bHi) {
        val2 = sv.z | ((dv.z & (NPB - 1)) << 17);
        lb2 = bkt - b0;
        int slot = atomicAdd(&qn[lb2], 1);
        if (slot < CAP) q[lb2 * QS + slot] = val2; else pend |= 4u;
      }
    }
    {
      int bkt = dv.w >> 7;
      if (dv.w >= 0 && bkt >= b0 && bkt < bHi) {
        val3 = sv.w | ((dv.w & (NPB - 1)) << 17);
        lb3 = bkt - b0;
        int slot = atomicAdd(&qn[lb3], 1);
        if (slot < CAP) q[lb3 * QS + slot] = val3; else pend |= 8u;
      }
    }
    for (;;) {
      __syncthreads();
      for (int b = t; b < nb; b += 256) {
        int n = qn[b];
        if (n >= CAP) {
          int pos = atomicAdd(&cursor[b0 + b], CAP);
#pragma unroll
          for (int j = 0; j < CAP; j++) be[pos + j] = q[b * QS + j];
          qn[b] = 0;
        }
      }
      if (!__syncthreads_or(pend ? 1 : 0)) break;
      if (pend & 1u) {
        int slot = atomicAdd(&qn[lb0], 1);
        if (slot < CAP) { q[lb0 * QS + slot] = val0; pend &= ~1u; }
      }
      if (pend & 2u) {
        int slot = atomicAdd(&qn[lb1], 1);
        if (slot < CAP) { q[lb1 * QS + slot] = val1; pend &= ~2u; }
      }
      if (pend & 4u) {
        int slot = atomicAdd(&qn[lb2], 1);
        if (slot < CAP) { q[lb2 * QS + slot] = val2; pend &= ~4u; }
      }
      if (pend & 8u) {
        int slot = atomicAdd(&qn[lb3], 1);
        if (slot < CAP) { q[lb3 * QS + slot] = val3; pend &= ~8u; }
      }
    }
  }
  for (int b = t; b < nb; b += 256) {
    int n = qn[b];
    if (n > 0) {
      int pos = atomicAdd(&cursor[b0 + b], n);
      for (int j = 0; j < n; j++) be[pos + j] = q[b * QS + j];
    }
  }
}

// per-bucket counting sort -> PADDED CSR (rows padded to x16 with index NN)
// + deg + rowptr + dinv + xs (= dinv*x premult). Raw entries occupy the first
// deg slots of each row; pads (NN -> zero feature row) fill to the x16 boundary.
__global__ __launch_bounds__(256) void k_sort(const int* __restrict__ binptr,
                                              const int* __restrict__ be,
                                              const float* __restrict__ x,
                                              int* __restrict__ csr,
                                              int* __restrict__ rowptr,
                                              int* __restrict__ deg,
                                              float* __restrict__ dinv,
                                              float* __restrict__ xs) {
  __shared__ int hist[NPB];
  __shared__ int excl[NPB];   // inclusive scan of padded sizes
  __shared__ int cur[NPB];
  __shared__ int sbase;
  int t = threadIdx.x, b = blockIdx.x;
  int e0 = binptr[b], e1 = binptr[b + 1];
  if (t < NPB) hist[t] = 0;
  if (t == 0) sbase = ((binptr[b] + BSTRIDE * b) + 15) & ~15;  // aligned bucket base
  __syncthreads();
  for (int k = e0 + t; k < e1; k += 256) atomicAdd(&hist[be[k] >> 17], 1);
  __syncthreads();
  if (t < NPB) excl[t] = (hist[t] + 15) & ~15;   // padded row size
  __syncthreads();
#pragma unroll
  for (int off = 1; off < NPB; off <<= 1) {
    int add = 0;
    if (t < NPB && t >= off) add = excl[t - off];
    __syncthreads();
    if (t < NPB) excl[t] += add;
    __syncthreads();
  }
  int base = sbase;
  if (t < NPB) {
    int psz = (hist[t] + 15) & ~15;
    int ex = excl[t] - psz;             // padded exclusive offset within bucket
    cur[t] = ex;
    int i = b * NPB + t;
    if (i < NN) {
      int dg = hist[t];
      deg[i] = dg;
      rowptr[i] = base + ex;            // x16-aligned row start
      float d = rsqrtf((float)dg + 1.0f);
      dinv[i] = d;
      float2 xv = ((const float2*)x)[i];
      ((float2*)xs)[i] = make_float2(d * xv.x, d * xv.y);
      for (int k2 = ex + dg; k2 < ex + psz; k2++) csr[base + k2] = NN;  // pads
    }
  }
  __syncthreads();
  for (int k = e0 + t; k < e1; k += 256) {
    int v = be[k];
    int pos = atomicAdd(&cur[v >> 17], 1);
    csr[base + pos] = v & 0x1FFFF;
  }
}

// ---------------- layers (premultiplied operands) ----------------

// layer 1: 4 lanes per node (1563 blocks), strided gather of xs, width-4
// shfl_xor reductions (all lanes active). Split 2x32 matvec 8 outputs/lane.
// Writes h1s = di * relu(LN(...))  (premultiplied for layer 2)
__global__ __launch_bounds__(256) void k_l1(const int* __restrict__ rowptr,
                                            const int* __restrict__ deg,
                                            const int* __restrict__ csr,
                                            const float* __restrict__ dinv,
                                            const float* __restrict__ xs,
                                            const float* __restrict__ w1,
                                            const float* __restrict__ b1,
                                            const float* __restrict__ g1,
                                            const float* __restrict__ be1,
                                            float* __restrict__ h1s) {
  __shared__ float w1s[64], b1s[32], g1s[32], be1s[32];
  int t = threadIdx.x;
  if (t < 64) w1s[t] = w1[t];
  if (t < 32) { b1s[t] = b1[t]; g1s[t] = g1[t]; be1s[t] = be1[t]; }
  __syncthreads();
  int gid = blockIdx.x * 256 + t;
  int i = gid >> 2, sub = gid & 3;
  if (i >= NN) return;
  const float2* xs2 = (const float2*)xs;
  float in0 = 0.f, in1 = 0.f;
  int r0 = rowptr[i], dg = deg[i];
  for (int k = sub; k < dg; k += 4) {
    int s = csr[r0 + k];
    float2 v = xs2[s];
    in0 += v.x; in1 += v.y;
  }
  in0 += __shfl_xor(in0, 1, 4); in0 += __shfl_xor(in0, 2, 4);
  in1 += __shfl_xor(in1, 1, 4); in1 += __shfl_xor(in1, 2, 4);
  float2 sv = xs2[i];
  in0 += sv.x; in1 += sv.y;               // self term (xs already has dinv)
  float di = dinv[i];
  float a0 = di * in0, a1 = di * in1;
  float h[8];
  int j0 = sub * 8;
  float mu = 0.f;
#pragma unroll
  for (int j = 0; j < 8; j++) {
    h[j] = fmaf(a0, w1s[j0 + j], fmaf(a1, w1s[32 + j0 + j], b1s[j0 + j]));
    mu += h[j];
  }
  mu += __shfl_xor(mu, 1, 4); mu += __shfl_xor(mu, 2, 4);
  mu *= (1.0f / HID);
  float var = 0.f;
#pragma unroll
  for (int j = 0; j < 8; j++) { float dd = h[j] - mu; var += dd * dd; }
  var += __shfl_xor(var, 1, 4); var += __shfl_xor(var, 2, 4);
  var *= (1.0f / HID);
  float rstd = rsqrtf(var + 1e-5f);
  float4* o4 = (float4*)(h1s + (size_t)i * HID + j0);
#pragma unroll
  for (int qq = 0; qq < 2; qq++) {
    float4 v;
    v.x = di * fmaxf(fmaf((h[4 * qq]     - mu) * rstd, g1s[j0 + 4 * qq],     be1s[j0 + 4 * qq]),     0.f);
    v.y = di * fmaxf(fmaf((h[4 * qq + 1] - mu) * rstd, g1s[j0 + 4 * qq + 1], be1s[j0 + 4 * qq + 1]), 0.f);
    v.z = di * fmaxf(fmaf((h[4 * qq + 2] - mu) * rstd, g1s[j0 + 4 * qq + 2], be1s[j0 + 4 * qq + 2]), 0.f);
    v.w = di * fmaxf(fmaf((h[4 * qq + 3] - mu) * rstd, g1s[j0 + 4 * qq + 3], be1s[j0 + 4 * qq + 3]), 0.f);
    o4[qq] = v;
  }
}

// layer 2: 32 lanes = one node; 8 nodes/block -> 12500 blocks.
// Padded CSR: per 16-edge tile, lane (jg,c4) does ONE int4 csr load (its quad
// of indices; pads point at zero row NN) + 4 unconditional float4 gathers +
// 4x4 adds. No selects/guards. Cross-slot reduce via shfl_xor 8/16; matvec
// from LDS broadcasts. Writes ps = dinv[i] * p[i] (premult for layer 3).
__global__ __launch_bounds__(256) void k_l2(const int* __restrict__ rowptr,
                                            const int* __restrict__ deg,
                                            const int* __restrict__ csr,
                                            const float* __restrict__ dinv,
                                            const float* __restrict__ h1s,
                                            const float* __restrict__ w2,
                                            const float* __restrict__ b2,
                                            const float* __restrict__ g2,
                                            const float* __restrict__ be2,
                                            const float* __restrict__ w3,
                                            float* __restrict__ ps) {
  __shared__ float w2s[HID * HID];
  __shared__ float b2s[32], g2s[32], be2s[32], w3s[32];
  __shared__ float aggl[8][HID];
  int t = threadIdx.x;
  for (int u = t; u < HID * HID; u += 256) w2s[u] = w2[u];
  if (t < 32) { b2s[t] = b2[t]; g2s[t] = g2[t]; be2s[t] = be2[t]; w3s[t] = w3[t]; }
  __syncthreads();
  int g = t >> 5;
  int L = t & 31;
  int i = blockIdx.x * 8 + g;          // node (grid exact: 12500*8 == NN)
  int jg = L >> 3, c4 = L & 7;
  const float4* h4 = (const float4*)h1s;
  float ax = 0.f, ay = 0.f, az = 0.f, aw = 0.f;
  if (jg == 0) {                        // self row once (premultiplied)
    float4 v = h4[(size_t)i * 8 + c4];
    ax += v.x; ay += v.y; az += v.z; aw += v.w;
  }
  int r0 = rowptr[i];
  int dgp = (deg[i] + 15) & ~15;        // padded row length (x16)
  for (int base = 0; base < dgp; base += 16) {
    int4 iv = *(const int4*)(csr + r0 + base + jg * 4);  // x16-aligned row
    float4 v0 = h4[(size_t)iv.x * 8 + c4];
    float4 v1 = h4[(size_t)iv.y * 8 + c4];
    float4 v2 = h4[(size_t)iv.z * 8 + c4];
    float4 v3 = h4[(size_t)iv.w * 8 + c4];
    ax += v0.x; ay += v0.y; az += v0.z; aw += v0.w;
    ax += v1.x; ay += v1.y; az += v1.z; aw += v1.w;
    ax += v2.x; ay += v2.y; az += v2.z; aw += v2.w;
    ax += v3.x; ay += v3.y; az += v3.z; aw += v3.w;
  }
  // reduce across the 4 edge-slots (xor 8 and xor 16 keep c4)
  ax += __shfl_xor(ax, 8, 32);  ay += __shfl_xor(ay, 8, 32);
  az += __shfl_xor(az, 8, 32);  aw += __shfl_xor(aw, 8, 32);
  ax += __shfl_xor(ax, 16, 32); ay += __shfl_xor(ay, 16, 32);
  az += __shfl_xor(az, 16, 32); aw += __shfl_xor(aw, 16, 32);
  float di = dinv[i];
  if (jg == 0) {
    aggl[g][c4 * 4 + 0] = di * ax;
    aggl[g][c4 * 4 + 1] = di * ay;
    aggl[g][c4 * 4 + 2] = di * az;
    aggl[g][c4 * 4 + 3] = di * aw;
  }
  __syncthreads();
  // matvec: h[f] = b2[f] + sum_k agg[k] * w2[k][f]
  float h = b2s[L];
#pragma unroll
  for (int k = 0; k < HID; k++) h = fmaf(aggl[g][k], w2s[k * HID + L], h);
  float mu = h;
#pragma unroll
  for (int off = 16; off > 0; off >>= 1) mu += __shfl_xor(mu, off, 32);
  mu *= (1.0f / HID);
  float dd = h - mu;
  float var = dd * dd;
#pragma unroll
  for (int off = 16; off > 0; off >>= 1) var += __shfl_xor(var, off, 32);
  var *= (1.0f / HID);
  float rstd = rsqrtf(var + 1e-5f);
  float v = fmaf(dd * rstd, g2s[L], be2s[L]);
  v = fmaxf(v, 0.0f);
  float pi = v * w3s[L];
#pragma unroll
  for (int off = 16; off > 0; off >>= 1) pi += __shfl_xor(pi, off, 32);
  if (L == 0) ps[i] = di * pi;
}

// layer 3: 4 lanes per node, strided sum of premultiplied ps
__global__ __launch_bounds__(256) void k_l3(const int* __restrict__ rowptr,
                                            const int* __restrict__ deg,
                                            const int* __restrict__ csr,
                                            const float* __restrict__ dinv,
                                            const float* __restrict__ ps,
                                            const float* __restrict__ b3,
                                            float* __restrict__ out) {
  int gid = blockIdx.x * 256 + threadIdx.x;
  int i = gid >> 2, sub = gid & 3;
  if (i >= NN) return;
  float inner = 0.f;
  int r0 = rowptr[i], dg = deg[i];
  for (int k = sub; k < dg; k += 4) inner += ps[csr[r0 + k]];
  inner += __shfl_xor(inner, 1, 4);
  inner += __shfl_xor(inner, 2, 4);
  inner += ps[i];                      // self term (premultiplied)
  if (sub == 0) out[i] = fmaf(dinv[i], inner, b3[0]);
}

// ---------------- launch ----------------

extern "C" void kernel_launch(void* const* d_in, const int* in_sizes, int n_in,
                              void* d_out, int out_size, void* d_ws, size_t ws_size,
                              hipStream_t stream) {
  const float* x   = (const float*)d_in[0];
  const int*   ei  = (const int*)d_in[1];
  const float* w1  = (const float*)d_in[2];
  const float* b1  = (const float*)d_in[3];
  const float* g1  = (const float*)d_in[4];
  const float* be1 = (const float*)d_in[5];
  const float* w2  = (const float*)d_in[6];
  const float* b2  = (const float*)d_in[7];
  const float* g2  = (const float*)d_in[8];
  const float* be2 = (const float*)d_in[9];
  const float* w3  = (const float*)d_in[10];
  const float* b3  = (const float*)d_in[11];
  float* out = (float*)d_out;

  char* wp = (char*)d_ws;
  auto alloc = [&](size_t bytes) {
    char* r = wp;
    wp += (bytes + 255) & ~size_t(255);
    return r;
  };
  int*   bincnt = (int*)alloc((size_t)NBIN * 4);
  int*   binptr = (int*)alloc((size_t)(NBIN + 1) * 4);
  int*   cursor = (int*)alloc((size_t)NBIN * 4);
  int*   bedge  = (int*)alloc((size_t)NE * 4);
  int*   csr    = (int*)alloc((size_t)(NE + (size_t)NBIN * BSTRIDE + 64) * 4);  // padded CSR
  int*   rowptr = (int*)alloc((size_t)NN * 4);
  int*   deg    = (int*)alloc((size_t)NN * 4);
  float* dinv   = (float*)alloc((size_t)NN * 4);
  float* xs     = (float*)alloc((size_t)NN * 2 * 4);
  float* h1s    = (float*)alloc((size_t)(NN + 1) * HID * 4);  // +1 zero pad row
  float* ps     = (float*)alloc((size_t)NN * 4);

  int bn4 = (NN * 4 + 255) / 256;   // 1563 blocks for 4-lane/node kernels

  hipMemsetAsync(bincnt, 0, (size_t)NBIN * 4, stream);
  hipMemsetAsync(h1s + (size_t)NN * HID, 0, HID * 4, stream);  // zero pad row
  k_binhist  <<<NB, 256, 0, stream>>>(ei, bincnt);
  k_binscan  <<<1, 1024, 0, stream>>>(bincnt, binptr, cursor);
  k_wcscatter<<<NCHUNK * NPART, 256, 0, stream>>>(ei, cursor, bedge);
  k_sort     <<<NBIN, 256, 0, stream>>>(binptr, bedge, x, csr, rowptr, deg, dinv, xs);
  k_l1       <<<bn4, 256, 0, stream>>>(rowptr, deg, csr, dinv, xs, w1, b1, g1, be1, h1s);
  k_l2       <<<NN / 8, 256, 0, stream>>>(rowptr, deg, csr, dinv, h1s,
                                          w2, b2, g2, be2, w3, ps);
  k_l3       <<<bn4, 256, 0, stream>>>(rowptr, deg, csr, dinv, ps, b3, out);
}

// Round 14
// 220.991 us; speedup vs baseline: 1.0253x; 1.0253x over previous
//
#include <hip/hip_runtime.h>
#include <hip/hip_fp16.h>

constexpr int NN  = 100000;   // nodes
constexpr int NE  = 1600000;  // edges
constexpr int NE4 = NE / 4;   // edge quads
constexpr int HID = 32;
constexpr int NPB = 128;                      // nodes per bucket (= 1<<7)
constexpr int NBIN = (NN + NPB - 1) / NPB;    // 782 buckets
constexpr int NB  = (NN + 255) / 256;         // 391

constexpr int NPART = 8;                      // XCD partitions
constexpr int PPB   = (NBIN + NPART - 1) / NPART;  // 98 buckets per partition
constexpr int NCHUNK = 120;                   // edge chunks (grid = 960)
constexpr int CAP   = 16;                     // queue entries = 64B flush chunk
constexpr int QS    = CAP + 1;                // padded stride (bank spread)

// ---------------- build: bucket scatter + per-bucket counting sort ----------------

__global__ __launch_bounds__(256) void k_binhist(const int* __restrict__ ei,
                                                 int* __restrict__ bincnt) {
  __shared__ int lh[NBIN];
  int t = threadIdx.x;
  for (int b = t; b < NBIN; b += 256) lh[b] = 0;
  __syncthreads();
  const int4* d4 = (const int4*)(ei + NE);
  for (int q = blockIdx.x * 256 + t; q < NE4; q += gridDim.x * 256) {
    int4 v = d4[q];
    atomicAdd(&lh[v.x >> 7], 1);
    atomicAdd(&lh[v.y >> 7], 1);
    atomicAdd(&lh[v.z >> 7], 1);
    atomicAdd(&lh[v.w >> 7], 1);
  }
  __syncthreads();
  for (int b = t; b < NBIN; b += 256) {
    int v = lh[b];
    if (v) atomicAdd(&bincnt[b], v);
  }
}

__global__ __launch_bounds__(1024) void k_binscan(const int* __restrict__ bincnt,
                                                  int* __restrict__ binptr,
                                                  int* __restrict__ cursor) {
  __shared__ int s[1024];
  int t = threadIdx.x;
  int v = (t < NBIN) ? bincnt[t] : 0;
  s[t] = v;
  __syncthreads();
#pragma unroll
  for (int off = 1; off < 1024; off <<= 1) {
    int add = (t >= off) ? s[t - off] : 0;
    __syncthreads();
    s[t] += add;
    __syncthreads();
  }
  if (t < NBIN) {
    int ex = s[t] - v;
    binptr[t] = ex;
    cursor[t] = ex;
  }
  if (t == NBIN - 1) binptr[NBIN] = s[t];
}

// LDS write-combining scatter, 4-edge coarsened; src loaded as int4
__global__ __launch_bounds__(256) void k_wcscatter(const int* __restrict__ ei,
                                                   int* __restrict__ cursor,
                                                   int* __restrict__ be) {
  __shared__ int q[PPB * QS];
  __shared__ int qn[PPB];
  int t = threadIdx.x;
  int part  = blockIdx.x & (NPART - 1);
  int chunk = blockIdx.x >> 3;
  int b0  = part * PPB;
  int bHi = min(b0 + PPB, NBIN);
  int nb  = bHi - b0;
  for (int b = t; b < nb; b += 256) qn[b] = 0;
  int q0 = (int)((long long)NE4 * chunk / NCHUNK);
  int q1 = (int)((long long)NE4 * (chunk + 1) / NCHUNK);
  const int4* d4 = (const int4*)(ei + NE);
  const int4* s4 = (const int4*)ei;
  __syncthreads();
  for (int qbase = q0; qbase < q1; qbase += 256) {
    int qi = qbase + t;
    int4 dv = make_int4(-1, -1, -1, -1);
    int4 sv = make_int4(0, 0, 0, 0);
    if (qi < q1) { dv = d4[qi]; sv = s4[qi]; }
    int val0 = 0, val1 = 0, val2 = 0, val3 = 0;
    int lb0 = 0, lb1 = 0, lb2 = 0, lb3 = 0;
    unsigned pend = 0;
    {
      int bkt = dv.x >> 7;
      if (dv.x >= 0 && bkt >= b0 && bkt < bHi) {
        val0 = sv.x | ((dv.x & (NPB - 1)) << 17);
        lb0 = bkt - b0;
        int slot = atomicAdd(&qn[lb0], 1);
        if (slot < CAP) q[lb0 * QS + slot] = val0; else pend |= 1u;
      }
    }
    {
      int bkt = dv.y >> 7;
      if (dv.y >= 0 && bkt >= b0 && bkt < bHi) {
        val1 = sv.y | ((dv.y & (NPB - 1)) << 17);
        lb1 = bkt - b0;
        int slot = atomicAdd(&qn[lb1], 1);
        if (slot < CAP) q[lb1 * QS + slot] = val1; else pend |= 2u;
      }
    }
    {
      int bkt = dv.z >> 7;
      if (dv.z >= 0 && bkt >= b0 && bkt < bHi) {
        val2 = sv.z | ((dv.z & (NPB - 1)) << 17);
        lb2 = bkt - b0;
        int slot = atomicAdd(&qn[lb2], 1);
        if (slot < CAP) q[lb2 * QS + slot] = val2; else pend |= 4u;
      }
    }
    {
      int bkt = dv.w >> 7;
      if (dv.w >= 0 && bkt >= b0 && bkt < bHi) {
        val3 = sv.w | ((dv.w & (NPB - 1)) << 17);
        lb3 = bkt - b0;
        int slot = atomicAdd(&qn[lb3], 1);
        if (slot < CAP) q[lb3 * QS + slot] = val3; else pend |= 8u;
      }
    }
    for (;;) {
      __syncthreads();
      for (int b = t; b < nb; b += 256) {
        int n = qn[b];
        if (n >= CAP) {
          int pos = atomicAdd(&cursor[b0 + b], CAP);
#pragma unroll
          for (int j = 0; j < CAP; j++) be[pos + j] = q[b * QS + j];
          qn[b] = 0;
        }
      }
      if (!__syncthreads_or(pend ? 1 : 0)) break;
      if (pend & 1u) {
        int slot = atomicAdd(&qn[lb0], 1);
        if (slot < CAP) { q[lb0 * QS + slot] = val0; pend &= ~1u; }
      }
      if (pend & 2u) {
        int slot = atomicAdd(&qn[lb1], 1);
        if (slot < CAP) { q[lb1 * QS + slot] = val1; pend &= ~2u; }
      }
      if (pend & 4u) {
        int slot = atomicAdd(&qn[lb2], 1);
        if (slot < CAP) { q[lb2 * QS + slot] = val2; pend &= ~4u; }
      }
      if (pend & 8u) {
        int slot = atomicAdd(&qn[lb3], 1);
        if (slot < CAP) { q[lb3 * QS + slot] = val3; pend &= ~8u; }
      }
    }
  }
  for (int b = t; b < nb; b += 256) {
    int n = qn[b];
    if (n > 0) {
      int pos = atomicAdd(&cursor[b0 + b], n);
      for (int j = 0; j < n; j++) be[pos + j] = q[b * QS + j];
    }
  }
}

// per-bucket counting sort -> CSR + deg + rowptr + dinv + xs (= dinv*x premult)
__global__ __launch_bounds__(256) void k_sort(const int* __restrict__ binptr,
                                              const int* __restrict__ be,
                                              const float* __restrict__ x,
                                              int* __restrict__ csr,
                                              int* __restrict__ rowptr,
                                              int* __restrict__ deg,
                                              float* __restrict__ dinv,
                                              float* __restrict__ xs) {
  __shared__ int hist[NPB];
  __shared__ int excl[NPB];
  __shared__ int cur[NPB];
  int t = threadIdx.x, b = blockIdx.x;
  int e0 = binptr[b], e1 = binptr[b + 1];
  if (t < NPB) hist[t] = 0;
  __syncthreads();
  for (int k = e0 + t; k < e1; k += 256) atomicAdd(&hist[be[k] >> 17], 1);
  __syncthreads();
  if (t < NPB) excl[t] = hist[t];
  __syncthreads();
#pragma unroll
  for (int off = 1; off < NPB; off <<= 1) {
    int add = 0;
    if (t < NPB && t >= off) add = excl[t - off];
    __syncthreads();
    if (t < NPB) excl[t] += add;
    __syncthreads();
  }
  if (t < NPB) {
    int ex = excl[t] - hist[t];
    cur[t] = ex;
    int i = b * NPB + t;
    if (i < NN) {
      int dg = hist[t];
      deg[i] = dg;
      rowptr[i] = e0 + ex;
      float d = rsqrtf((float)dg + 1.0f);
      dinv[i] = d;
      float2 xv = ((const float2*)x)[i];
      ((float2*)xs)[i] = make_float2(d * xv.x, d * xv.y);
    }
  }
  __syncthreads();
  for (int k = e0 + t; k < e1; k += 256) {
    int v = be[k];
    int pos = atomicAdd(&cur[v >> 17], 1);
    csr[e0 + pos] = v & 0x1FFFF;
  }
}

// ---------------- layers (premultiplied operands; h1s stored fp16) ----------------

// layer 1: per-node thread, 4x-batched gather of xs (order-preserving ILP).
// Writes h1s = fp16( di * relu(LN(...)) )  (premultiplied for layer 2)
__global__ __launch_bounds__(256) void k_l1(const int* __restrict__ rowptr,
                                            const int* __restrict__ deg,
                                            const int* __restrict__ csr,
                                            const float* __restrict__ dinv,
                                            const float* __restrict__ xs,
                                            const float* __restrict__ w1,
                                            const float* __restrict__ b1,
                                            const float* __restrict__ g1,
                                            const float* __restrict__ be1,
                                            __half* __restrict__ h1s) {
  __shared__ float w1s[64], b1s[32], g1s[32], be1s[32];
  int t = threadIdx.x;
  if (t < 64) w1s[t] = w1[t];
  if (t < 32) { b1s[t] = b1[t]; g1s[t] = g1[t]; be1s[t] = be1[t]; }
  __syncthreads();
  int i = blockIdx.x * 256 + t;
  if (i >= NN) return;
  const float2* xs2 = (const float2*)xs;
  float2 sv = xs2[i];
  float in0 = sv.x, in1 = sv.y;           // self term (xs already has dinv)
  int r0 = rowptr[i], dg = deg[i];
  int k = 0;
  for (; k + 4 <= dg; k += 4) {           // 4 independent loads, ordered adds
    int s0 = csr[r0 + k], s1 = csr[r0 + k + 1];
    int s2 = csr[r0 + k + 2], s3 = csr[r0 + k + 3];
    float2 v0 = xs2[s0], v1 = xs2[s1], v2 = xs2[s2], v3 = xs2[s3];
    in0 += v0.x; in1 += v0.y;
    in0 += v1.x; in1 += v1.y;
    in0 += v2.x; in1 += v2.y;
    in0 += v3.x; in1 += v3.y;
  }
  for (; k < dg; k++) {
    int s = csr[r0 + k];
    float2 v = xs2[s];
    in0 += v.x; in1 += v.y;
  }
  float di = dinv[i];
  float a0 = di * in0, a1 = di * in1;
  float h[HID];
  float mu = 0.f;
#pragma unroll
  for (int j = 0; j < HID; j++) {
    h[j] = fmaf(a0, w1s[j], fmaf(a1, w1s[32 + j], b1s[j]));
    mu += h[j];
  }
  mu *= (1.0f / HID);
  float var = 0.f;
#pragma unroll
  for (int j = 0; j < HID; j++) { float dd = h[j] - mu; var += dd * dd; }
  var *= (1.0f / HID);
  float rstd = rsqrtf(var + 1e-5f);
  __half2* o2 = (__half2*)(h1s + (size_t)i * HID);
#pragma unroll
  for (int q = 0; q < 8; q++) {
    float vx = di * fmaxf(fmaf((h[4 * q]     - mu) * rstd, g1s[4 * q],     be1s[4 * q]),     0.f);
    float vy = di * fmaxf(fmaf((h[4 * q + 1] - mu) * rstd, g1s[4 * q + 1], be1s[4 * q + 1]), 0.f);
    float vz = di * fmaxf(fmaf((h[4 * q + 2] - mu) * rstd, g1s[4 * q + 2], be1s[4 * q + 2]), 0.f);
    float vw = di * fmaxf(fmaf((h[4 * q + 3] - mu) * rstd, g1s[4 * q + 3], be1s[4 * q + 3]), 0.f);
    o2[2 * q]     = __floats2half2_rn(vx, vy);
    o2[2 * q + 1] = __floats2half2_rn(vz, vw);
  }
}

// layer 2: 32 lanes = one node; 8 nodes/block -> 12500 blocks.
// Lane L = (edge-slot jg = L>>3, feature-quad c4 = L&7). Per 4 edges:
// broadcast csr read + select-to-pad + one 8B fp16x4 gather (8 lanes x 8B =
// full 64B row) + f32 accumulate. Tail lanes use row NN (zeros). Cross-slot
// reduce via shfl_xor 8/16; matvec from LDS broadcasts.
// Writes ps = dinv[i] * p[i] (premult for layer 3).
__global__ __launch_bounds__(256) void k_l2(const int* __restrict__ rowptr,
                                            const int* __restrict__ deg,
                                            const int* __restrict__ csr,
                                            const float* __restrict__ dinv,
                                            const __half* __restrict__ h1s,
                                            const float* __restrict__ w2,
                                            const float* __restrict__ b2,
                                            const float* __restrict__ g2,
                                            const float* __restrict__ be2,
                                            const float* __restrict__ w3,
                                            float* __restrict__ ps) {
  __shared__ float w2s[HID * HID];
  __shared__ float b2s[32], g2s[32], be2s[32], w3s[32];
  __shared__ float aggl[8][HID];
  int t = threadIdx.x;
  for (int u = t; u < HID * HID; u += 256) w2s[u] = w2[u];
  if (t < 32) { b2s[t] = b2[t]; g2s[t] = g2[t]; be2s[t] = be2[t]; w3s[t] = w3[t]; }
  __syncthreads();
  int g = t >> 5;
  int L = t & 31;
  int i = blockIdx.x * 8 + g;          // node (grid exact: 12500*8 == NN)
  int jg = L >> 3, c4 = L & 7;
  float ax = 0.f, ay = 0.f, az = 0.f, aw = 0.f;
  auto gather = [&](int s) {
    float2 raw = *(const float2*)(h1s + (size_t)s * HID + c4 * 4);  // 4 halfs
    __half2 p0 = *(__half2*)&raw.x;
    __half2 p1 = *(__half2*)&raw.y;
    float2 f0 = __half22float2(p0);
    float2 f1 = __half22float2(p1);
    ax += f0.x; ay += f0.y; az += f1.x; aw += f1.y;
  };
  if (jg == 0) gather(i);               // self row once (premultiplied)
  int r0 = rowptr[i], dg = deg[i];
  for (int base = 0; base < dg; base += 16) {
#pragma unroll
    for (int it = 0; it < 4; it++) {
      int kk = base + it * 4 + jg;
      int sv = csr[r0 + kk];            // csr has +32 slack; over-reads safe
      int s = (kk < dg) ? sv : NN;      // pad -> zero row
      gather(s);
    }
  }
  // reduce across the 4 edge-slots (xor 8 and xor 16 keep c4)
  ax += __shfl_xor(ax, 8, 32);  ay += __shfl_xor(ay, 8, 32);
  az += __shfl_xor(az, 8, 32);  aw += __shfl_xor(aw, 8, 32);
  ax += __shfl_xor(ax, 16, 32); ay += __shfl_xor(ay, 16, 32);
  az += __shfl_xor(az, 16, 32); aw += __shfl_xor(aw, 16, 32);
  float di = dinv[i];
  if (jg == 0) {
    aggl[g][c4 * 4 + 0] = di * ax;
    aggl[g][c4 * 4 + 1] = di * ay;
    aggl[g][c4 * 4 + 2] = di * az;
    aggl[g][c4 * 4 + 3] = di * aw;
  }
  __syncthreads();
  // matvec: h[f] = b2[f] + sum_k agg[k] * w2[k][f]
  float h = b2s[L];
#pragma unroll
  for (int k = 0; k < HID; k++) h = fmaf(aggl[g][k], w2s[k * HID + L], h);
  float mu = h;
#pragma unroll
  for (int off = 16; off > 0; off >>= 1) mu += __shfl_xor(mu, off, 32);
  mu *= (1.0f / HID);
  float dd = h - mu;
  float var = dd * dd;
#pragma unroll
  for (int off = 16; off > 0; off >>= 1) var += __shfl_xor(var, off, 32);
  var *= (1.0f / HID);
  float rstd = rsqrtf(var + 1e-5f);
  float v = fmaf(dd * rstd, g2s[L], be2s[L]);
  v = fmaxf(v, 0.0f);
  float pi = v * w3s[L];
#pragma unroll
  for (int off = 16; off > 0; off >>= 1) pi += __shfl_xor(pi, off, 32);
  if (L == 0) ps[i] = di * pi;
}

// layer 3: per-node thread, 4x-batched sum of premultiplied ps
__global__ __launch_bounds__(256) void k_l3(const int* __restrict__ rowptr,
                                            const int* __restrict__ deg,
                                            const int* __restrict__ csr,
                                            const float* __restrict__ dinv,
                                            const float* __restrict__ ps,
                                            const float* __restrict__ b3,
                                            float* __restrict__ out) {
  int i = blockIdx.x * 256 + threadIdx.x;
  if (i >= NN) return;
  float inner = ps[i];                 // self term (premultiplied)
  int r0 = rowptr[i], dg = deg[i];
  int k = 0;
  for (; k + 4 <= dg; k += 4) {
    float v0 = ps[csr[r0 + k]],     v1 = ps[csr[r0 + k + 1]];
    float v2 = ps[csr[r0 + k + 2]], v3 = ps[csr[r0 + k + 3]];
    inner += v0; inner += v1; inner += v2; inner += v3;
  }
  for (; k < dg; k++) inner += ps[csr[r0 + k]];
  out[i] = fmaf(dinv[i], inner, b3[0]);
}

// ---------------- launch ----------------

extern "C" void kernel_launch(void* const* d_in, const int* in_sizes, int n_in,
                              void* d_out, int out_size, void* d_ws, size_t ws_size,
                              hipStream_t stream) {
  const float* x   = (const float*)d_in[0];
  const int*   ei  = (const int*)d_in[1];
  const float* w1  = (const float*)d_in[2];
  const float* b1  = (const float*)d_in[3];
  const float* g1  = (const float*)d_in[4];
  const float* be1 = (const float*)d_in[5];
  const float* w2  = (const float*)d_in[6];
  const float* b2  = (const float*)d_in[7];
  const float* g2  = (const float*)d_in[8];
  const float* be2 = (const float*)d_in[9];
  const float* w3  = (const float*)d_in[10];
  const float* b3  = (const float*)d_in[11];
  float* out = (float*)d_out;

  char* wp = (char*)d_ws;
  auto alloc = [&](size_t bytes) {
    char* r = wp;
    wp += (bytes + 255) & ~size_t(255);
    return r;
  };
  int*    bincnt = (int*)alloc((size_t)NBIN * 4);
  int*    binptr = (int*)alloc((size_t)(NBIN + 1) * 4);
  int*    cursor = (int*)alloc((size_t)NBIN * 4);
  int*    bedge  = (int*)alloc((size_t)NE * 4);
  int*    csr    = (int*)alloc((size_t)(NE + 32) * 4);      // +32 slack for k_l2 over-read
  int*    rowptr = (int*)alloc((size_t)NN * 4);
  int*    deg    = (int*)alloc((size_t)NN * 4);
  float*  dinv   = (float*)alloc((size_t)NN * 4);
  float*  xs     = (float*)alloc((size_t)NN * 2 * 4);
  __half* h1s    = (__half*)alloc((size_t)(NN + 1) * HID * 2);  // fp16, +1 zero pad row
  float*  ps     = (float*)alloc((size_t)NN * 4);

  hipMemsetAsync(bincnt, 0, (size_t)NBIN * 4, stream);
  hipMemsetAsync(h1s + (size_t)NN * HID, 0, HID * 2, stream);  // zero pad row
  k_binhist  <<<NB, 256, 0, stream>>>(ei, bincnt);
  k_binscan  <<<1, 1024, 0, stream>>>(bincnt, binptr, cursor);
  k_wcscatter<<<NCHUNK * NPART, 256, 0, stream>>>(ei, cursor, bedge);
  k_sort     <<<NBIN, 256, 0, stream>>>(binptr, bedge, x, csr, rowptr, deg, dinv, xs);
  k_l1       <<<NB, 256, 0, stream>>>(rowptr, deg, csr, dinv, xs, w1, b1, g1, be1, h1s);
  k_l2       <<<NN / 8, 256, 0, stream>>>(rowptr, deg, csr, dinv, h1s,
                                          w2, b2, g2, be2, w3, ps);
  k_l3       <<<NB, 256, 0, stream>>>(rowptr, deg, csr, dinv, ps, b3, out);
}

// Round 16
// 219.384 us; speedup vs baseline: 1.0328x; 1.0073x over previous
//
#include <hip/hip_runtime.h>
#include <hip/hip_fp16.h>

constexpr int NN  = 100000;   // nodes
constexpr int NE  = 1600000;  // edges
constexpr int NE4 = NE / 4;   // edge quads
constexpr int HID = 32;
constexpr int NPB = 128;                      // nodes per bucket (= 1<<7)
constexpr int NBIN = (NN + NPB - 1) / NPB;    // 782 buckets
constexpr int NB  = (NN + 255) / 256;         // 391

constexpr int NPART = 8;                      // XCD partitions
constexpr int PPB   = (NBIN + NPART - 1) / NPART;  // 98 buckets per partition
constexpr int NCHUNK = 240;                   // edge chunks (grid = 1920)
constexpr int CAP   = 16;                     // queue entries = 64B flush chunk
constexpr int QS    = CAP + 1;                // padded stride (bank spread)
constexpr int BSTRIDE = 2048;                 // extra csr slots per bucket (row padding)

// ---------------- build: bucket scatter + per-bucket counting sort ----------------

__global__ __launch_bounds__(256) void k_binhist(const int* __restrict__ ei,
                                                 int* __restrict__ bincnt) {
  __shared__ int lh[NBIN];
  int t = threadIdx.x;
  for (int b = t; b < NBIN; b += 256) lh[b] = 0;
  __syncthreads();
  const int4* d4 = (const int4*)(ei + NE);
  for (int q = blockIdx.x * 256 + t; q < NE4; q += gridDim.x * 256) {
    int4 v = d4[q];
    atomicAdd(&lh[v.x >> 7], 1);
    atomicAdd(&lh[v.y >> 7], 1);
    atomicAdd(&lh[v.z >> 7], 1);
    atomicAdd(&lh[v.w >> 7], 1);
  }
  __syncthreads();
  for (int b = t; b < NBIN; b += 256) {
    int v = lh[b];
    if (v) atomicAdd(&bincnt[b], v);
  }
}

__global__ __launch_bounds__(1024) void k_binscan(const int* __restrict__ bincnt,
                                                  int* __restrict__ binptr,
                                                  int* __restrict__ cursor) {
  __shared__ int s[1024];
  int t = threadIdx.x;
  int v = (t < NBIN) ? bincnt[t] : 0;
  s[t] = v;
  __syncthreads();
#pragma unroll
  for (int off = 1; off < 1024; off <<= 1) {
    int add = (t >= off) ? s[t - off] : 0;
    __syncthreads();
    s[t] += add;
    __syncthreads();
  }
  if (t < NBIN) {
    int ex = s[t] - v;
    binptr[t] = ex;
    cursor[t] = ex;
  }
  if (t == NBIN - 1) binptr[NBIN] = s[t];
}

// LDS write-combining scatter, 4-edge coarsened; conditional int4 src load
__global__ __launch_bounds__(256) void k_wcscatter(const int* __restrict__ ei,
                                                   int* __restrict__ cursor,
                                                   int* __restrict__ be) {
  __shared__ int q[PPB * QS];
  __shared__ int qn[PPB];
  int t = threadIdx.x;
  int part  = blockIdx.x & (NPART - 1);
  int chunk = blockIdx.x >> 3;
  int b0  = part * PPB;
  int bHi = min(b0 + PPB, NBIN);
  int nb  = bHi - b0;
  for (int b = t; b < nb; b += 256) qn[b] = 0;
  int q0 = (int)((long long)NE4 * chunk / NCHUNK);
  int q1 = (int)((long long)NE4 * (chunk + 1) / NCHUNK);
  const int4* d4 = (const int4*)(ei + NE);
  const int4* s4 = (const int4*)ei;
  __syncthreads();
  for (int qbase = q0; qbase < q1; qbase += 256) {
    int qi = qbase + t;
    int4 dv = make_int4(-1, -1, -1, -1);
    if (qi < q1) dv = d4[qi];
    bool in0 = dv.x >= 0 && (dv.x >> 7) >= b0 && (dv.x >> 7) < bHi;
    bool in1 = dv.y >= 0 && (dv.y >> 7) >= b0 && (dv.y >> 7) < bHi;
    bool in2 = dv.z >= 0 && (dv.z >> 7) >= b0 && (dv.z >> 7) < bHi;
    bool in3 = dv.w >= 0 && (dv.w >> 7) >= b0 && (dv.w >> 7) < bHi;
    int4 sv = make_int4(0, 0, 0, 0);
    if (in0 || in1 || in2 || in3) sv = s4[qi];   // load src only when needed
    int val0 = 0, val1 = 0, val2 = 0, val3 = 0;
    int lb0 = 0, lb1 = 0, lb2 = 0, lb3 = 0;
    unsigned pend = 0;
    if (in0) {
      val0 = sv.x | ((dv.x & (NPB - 1)) << 17);
      lb0 = (dv.x >> 7) - b0;
      int slot = atomicAdd(&qn[lb0], 1);
      if (slot < CAP) q[lb0 * QS + slot] = val0; else pend |= 1u;
    }
    if (in1) {
      val1 = sv.y | ((dv.y & (NPB - 1)) << 17);
      lb1 = (dv.y >> 7) - b0;
      int slot = atomicAdd(&qn[lb1], 1);
      if (slot < CAP) q[lb1 * QS + slot] = val1; else pend |= 2u;
    }
    if (in2) {
      val2 = sv.z | ((dv.z & (NPB - 1)) << 17);
      lb2 = (dv.z >> 7) - b0;
      int slot = atomicAdd(&qn[lb2], 1);
      if (slot < CAP) q[lb2 * QS + slot] = val2; else pend |= 4u;
    }
    if (in3) {
      val3 = sv.w | ((dv.w & (NPB - 1)) << 17);
      lb3 = (dv.w >> 7) - b0;
      int slot = atomicAdd(&qn[lb3], 1);
      if (slot < CAP) q[lb3 * QS + slot] = val3; else pend |= 8u;
    }
    for (;;) {
      __syncthreads();
      for (int b = t; b < nb; b += 256) {
        int n = qn[b];
        if (n >= CAP) {
          int pos = atomicAdd(&cursor[b0 + b], CAP);
#pragma unroll
          for (int j = 0; j < CAP; j++) be[pos + j] = q[b * QS + j];
          qn[b] = 0;
        }
      }
      if (!__syncthreads_or(pend ? 1 : 0)) break;
      if (pend & 1u) {
        int slot = atomicAdd(&qn[lb0], 1);
        if (slot < CAP) { q[lb0 * QS + slot] = val0; pend &= ~1u; }
      }
      if (pend & 2u) {
        int slot = atomicAdd(&qn[lb1], 1);
        if (slot < CAP) { q[lb1 * QS + slot] = val1; pend &= ~2u; }
      }
      if (pend & 4u) {
        int slot = atomicAdd(&qn[lb2], 1);
        if (slot < CAP) { q[lb2 * QS + slot] = val2; pend &= ~4u; }
      }
      if (pend & 8u) {
        int slot = atomicAdd(&qn[lb3], 1);
        if (slot < CAP) { q[lb3 * QS + slot] = val3; pend &= ~8u; }
      }
    }
  }
  for (int b = t; b < nb; b += 256) {
    int n = qn[b];
    if (n > 0) {
      int pos = atomicAdd(&cursor[b0 + b], n);
      for (int j = 0; j < n; j++) be[pos + j] = q[b * QS + j];
    }
  }
}

// per-bucket counting sort -> PADDED CSR (rows padded to x16 with index NN,
// 16-aligned row starts) + deg + rowptr + dinv + xs (= dinv*x premult)
__global__ __launch_bounds__(256) void k_sort(const int* __restrict__ binptr,
                                              const int* __restrict__ be,
                                              const float* __restrict__ x,
                                              int* __restrict__ csr,
                                              int* __restrict__ rowptr,
                                              int* __restrict__ deg,
                                              float* __restrict__ dinv,
                                              float* __restrict__ xs) {
  __shared__ int hist[NPB];
  __shared__ int excl[NPB];   // inclusive scan of padded sizes
  __shared__ int cur[NPB];
  __shared__ int sbase;
  int t = threadIdx.x, b = blockIdx.x;
  int e0 = binptr[b], e1 = binptr[b + 1];
  if (t < NPB) hist[t] = 0;
  if (t == 0) sbase = ((binptr[b] + BSTRIDE * b) + 15) & ~15;  // aligned bucket base
  __syncthreads();
  for (int k = e0 + t; k < e1; k += 256) atomicAdd(&hist[be[k] >> 17], 1);
  __syncthreads();
  if (t < NPB) excl[t] = (hist[t] + 15) & ~15;   // padded row size
  __syncthreads();
#pragma unroll
  for (int off = 1; off < NPB; off <<= 1) {
    int add = 0;
    if (t < NPB && t >= off) add = excl[t - off];
    __syncthreads();
    if (t < NPB) excl[t] += add;
    __syncthreads();
  }
  int base = sbase;
  if (t < NPB) {
    int psz = (hist[t] + 15) & ~15;
    int ex = excl[t] - psz;             // padded exclusive offset within bucket
    cur[t] = ex;
    int i = b * NPB + t;
    if (i < NN) {
      int dg = hist[t];
      deg[i] = dg;
      rowptr[i] = base + ex;            // x16-aligned row start
      float d = rsqrtf((float)dg + 1.0f);
      dinv[i] = d;
      float2 xv = ((const float2*)x)[i];
      ((float2*)xs)[i] = make_float2(d * xv.x, d * xv.y);
      for (int k2 = ex + dg; k2 < ex + psz; k2++) csr[base + k2] = NN;  // pads
    }
  }
  __syncthreads();
  for (int k = e0 + t; k < e1; k += 256) {
    int v = be[k];
    int pos = atomicAdd(&cur[v >> 17], 1);
    csr[base + pos] = v & 0x1FFFF;
  }
}

// ---------------- layers (premultiplied operands; h1s stored fp16) ----------------

// layer 1: per-node thread, 4x-batched gather of xs (order-preserving ILP).
// Writes h1s = fp16( di * relu(LN(...)) )  (premultiplied for layer 2)
__global__ __launch_bounds__(256) void k_l1(const int* __restrict__ rowptr,
                                            const int* __restrict__ deg,
                                            const int* __restrict__ csr,
                                            const float* __restrict__ dinv,
                                            const float* __restrict__ xs,
                                            const float* __restrict__ w1,
                                            const float* __restrict__ b1,
                                            const float* __restrict__ g1,
                                            const float* __restrict__ be1,
                                            __half* __restrict__ h1s) {
  __shared__ float w1s[64], b1s[32], g1s[32], be1s[32];
  int t = threadIdx.x;
  if (t < 64) w1s[t] = w1[t];
  if (t < 32) { b1s[t] = b1[t]; g1s[t] = g1[t]; be1s[t] = be1[t]; }
  __syncthreads();
  int i = blockIdx.x * 256 + t;
  if (i >= NN) return;
  const float2* xs2 = (const float2*)xs;
  float2 sv = xs2[i];
  float in0 = sv.x, in1 = sv.y;           // self term (xs already has dinv)
  int r0 = rowptr[i], dg = deg[i];
  int k = 0;
  for (; k + 4 <= dg; k += 4) {           // 4 independent loads, ordered adds
    int s0 = csr[r0 + k], s1 = csr[r0 + k + 1];
    int s2 = csr[r0 + k + 2], s3 = csr[r0 + k + 3];
    float2 v0 = xs2[s0], v1 = xs2[s1], v2 = xs2[s2], v3 = xs2[s3];
    in0 += v0.x; in1 += v0.y;
    in0 += v1.x; in1 += v1.y;
    in0 += v2.x; in1 += v2.y;
    in0 += v3.x; in1 += v3.y;
  }
  for (; k < dg; k++) {
    int s = csr[r0 + k];
    float2 v = xs2[s];
    in0 += v.x; in1 += v.y;
  }
  float di = dinv[i];
  float a0 = di * in0, a1 = di * in1;
  float h[HID];
  float mu = 0.f;
#pragma unroll
  for (int j = 0; j < HID; j++) {
    h[j] = fmaf(a0, w1s[j], fmaf(a1, w1s[32 + j], b1s[j]));
    mu += h[j];
  }
  mu *= (1.0f / HID);
  float var = 0.f;
#pragma unroll
  for (int j = 0; j < HID; j++) { float dd = h[j] - mu; var += dd * dd; }
  var *= (1.0f / HID);
  float rstd = rsqrtf(var + 1e-5f);
  __half2* o2 = (__half2*)(h1s + (size_t)i * HID);
#pragma unroll
  for (int q = 0; q < 8; q++) {
    float vx = di * fmaxf(fmaf((h[4 * q]     - mu) * rstd, g1s[4 * q],     be1s[4 * q]),     0.f);
    float vy = di * fmaxf(fmaf((h[4 * q + 1] - mu) * rstd, g1s[4 * q + 1], be1s[4 * q + 1]), 0.f);
    float vz = di * fmaxf(fmaf((h[4 * q + 2] - mu) * rstd, g1s[4 * q + 2], be1s[4 * q + 2]), 0.f);
    float vw = di * fmaxf(fmaf((h[4 * q + 3] - mu) * rstd, g1s[4 * q + 3], be1s[4 * q + 3]), 0.f);
    o2[2 * q]     = __floats2half2_rn(vx, vy);
    o2[2 * q + 1] = __floats2half2_rn(vz, vw);
  }
}

// layer 2 v3: 32 lanes = one node; 8 nodes/block -> 12500 blocks.
// Lane L = (jg = L>>2 edge-slot, c4 = L&3 feature-oct). Per 32-edge tile:
// ONE int4 csr load per lane (row is x16-padded & 16-aligned; out-of-range jg
// selects zero-row NN) then 4 independent 16B gathers (4 lanes x 16B = 64B
// row). Most nodes: 1 csr-wait + 1 gather-wait total. Reduce over jg = 3
// shfl_xor rounds; matvec sources agg via compile-time-lane shfl (no LDS,
// no barrier); LN mean/var fused single pass.
// Writes ps = dinv[i] * p[i] (premult for layer 3).
__global__ __launch_bounds__(256) void k_l2(const int* __restrict__ rowptr,
                                            const int* __restrict__ deg,
                                            const int* __restrict__ csr,
                                            const float* __restrict__ dinv,
                                            const __half* __restrict__ h1s,
                                            const float* __restrict__ w2,
                                            const float* __restrict__ b2,
                                            const float* __restrict__ g2,
                                            const float* __restrict__ be2,
                                            const float* __restrict__ w3,
                                            float* __restrict__ ps) {
  __shared__ float w2s[HID * HID];
  __shared__ float b2s[32], g2s[32], be2s[32], w3s[32];
  int t = threadIdx.x;
  for (int u = t; u < HID * HID; u += 256) w2s[u] = w2[u];
  if (t < 32) { b2s[t] = b2[t]; g2s[t] = g2[t]; be2s[t] = be2[t]; w3s[t] = w3[t]; }
  __syncthreads();
  int g = t >> 5;
  int L = t & 31;
  int i = blockIdx.x * 8 + g;          // node (grid exact: 12500*8 == NN)
  int jg = L >> 2, c4 = L & 3;         // 8 edge-slots x 4 feature-octs
  float a0 = 0.f, a1 = 0.f, a2 = 0.f, a3 = 0.f;
  float a4 = 0.f, a5 = 0.f, a6 = 0.f, a7 = 0.f;
  auto gather = [&](int s) {
    float4 raw = *(const float4*)(h1s + (size_t)s * HID + c4 * 8);  // 8 halfs
    __half2 p0 = *(__half2*)&raw.x;
    __half2 p1 = *(__half2*)&raw.y;
    __half2 p2 = *(__half2*)&raw.z;
    __half2 p3 = *(__half2*)&raw.w;
    float2 f0 = __half22float2(p0);
    float2 f1 = __half22float2(p1);
    float2 f2 = __half22float2(p2);
    float2 f3 = __half22float2(p3);
    a0 += f0.x; a1 += f0.y; a2 += f1.x; a3 += f1.y;
    a4 += f2.x; a5 += f2.y; a6 += f3.x; a7 += f3.y;
  };
  if (jg == 0) gather(i);               // self row once (4 lanes cover 64B)
  int r0 = rowptr[i];
  int dgp = (deg[i] + 15) & ~15;        // padded row length (x16)
  const int4* csr4 = (const int4*)(csr + r0);   // r0 is x16 -> 16B aligned
  for (int base = 0; base < dgp; base += 32) {
    int rem = dgp - base;
    int4 iv = (jg * 4 < rem) ? csr4[(base >> 2) + jg]
                             : make_int4(NN, NN, NN, NN);
    gather(iv.x);
    gather(iv.y);
    gather(iv.z);
    gather(iv.w);
  }
  // reduce across the 8 jg slots (xor 4, 8, 16 keep c4)
#pragma unroll
  for (int off = 4; off <= 16; off <<= 1) {
    a0 += __shfl_xor(a0, off, 32); a1 += __shfl_xor(a1, off, 32);
    a2 += __shfl_xor(a2, off, 32); a3 += __shfl_xor(a3, off, 32);
    a4 += __shfl_xor(a4, off, 32); a5 += __shfl_xor(a5, off, 32);
    a6 += __shfl_xor(a6, off, 32); a7 += __shfl_xor(a7, off, 32);
  }
  float di = dinv[i];
  a0 *= di; a1 *= di; a2 *= di; a3 *= di;
  a4 *= di; a5 *= di; a6 *= di; a7 *= di;
  // matvec: h[L] = b2[L] + sum_k agg[k] * w2[k][L]; agg[k] lives in reg (k&7)
  // of lane (jg=0, c4=k>>3) == lane k>>3.
  float h = b2s[L];
#pragma unroll
  for (int k = 0; k < HID; k++) {
    float src;
    switch (k & 7) {
      case 0: src = a0; break;
      case 1: src = a1; break;
      case 2: src = a2; break;
      case 3: src = a3; break;
      case 4: src = a4; break;
      case 5: src = a5; break;
      case 6: src = a6; break;
      default: src = a7; break;
    }
    float ak = __shfl(src, k >> 3, 32);
    h = fmaf(ak, w2s[k * HID + L], h);
  }
  // fused LN stats: one reduction pass for (sum, sumsq)
  float s1 = h, s2 = h * h;
#pragma unroll
  for (int off = 16; off > 0; off >>= 1) {
    s1 += __shfl_xor(s1, off, 32);
    s2 += __shfl_xor(s2, off, 32);
  }
  float mu = s1 * (1.0f / HID);
  float var = fmaxf(s2 * (1.0f / HID) - mu * mu, 0.0f);
  float rstd = rsqrtf(var + 1e-5f);
  float v = fmaf((h - mu) * rstd, g2s[L], be2s[L]);
  v = fmaxf(v, 0.0f);
  float pi = v * w3s[L];
#pragma unroll
  for (int off = 16; off > 0; off >>= 1) pi += __shfl_xor(pi, off, 32);
  if (L == 0) ps[i] = di * pi;
}

// layer 3: per-node thread, 4x-batched sum of premultiplied ps
__global__ __launch_bounds__(256) void k_l3(const int* __restrict__ rowptr,
                                            const int* __restrict__ deg,
                                            const int* __restrict__ csr,
                                            const float* __restrict__ dinv,
                                            const float* __restrict__ ps,
                                            const float* __restrict__ b3,
                                            float* __restrict__ out) {
  int i = blockIdx.x * 256 + threadIdx.x;
  if (i >= NN) return;
  float inner = ps[i];                 // self term (premultiplied)
  int r0 = rowptr[i], dg = deg[i];
  int k = 0;
  for (; k + 4 <= dg; k += 4) {
    float v0 = ps[csr[r0 + k]],     v1 = ps[csr[r0 + k + 1]];
    float v2 = ps[csr[r0 + k + 2]], v3 = ps[csr[r0 + k + 3]];
    inner += v0; inner += v1; inner += v2; inner += v3;
  }
  for (; k < dg; k++) inner += ps[csr[r0 + k]];
  out[i] = fmaf(dinv[i], inner, b3[0]);
}

// ---------------- launch ----------------

extern "C" void kernel_launch(void* const* d_in, const int* in_sizes, int n_in,
                              void* d_out, int out_size, void* d_ws, size_t ws_size,
                              hipStream_t stream) {
  const float* x   = (const float*)d_in[0];
  const int*   ei  = (const int*)d_in[1];
  const float* w1  = (const float*)d_in[2];
  const float* b1  = (const float*)d_in[3];
  const float* g1  = (const float*)d_in[4];
  const float* be1 = (const float*)d_in[5];
  const float* w2  = (const float*)d_in[6];
  const float* b2  = (const float*)d_in[7];
  const float* g2  = (const float*)d_in[8];
  const float* be2 = (const float*)d_in[9];
  const float* w3  = (const float*)d_in[10];
  const float* b3  = (const float*)d_in[11];
  float* out = (float*)d_out;

  char* wp = (char*)d_ws;
  auto alloc = [&](size_t bytes) {
    char* r = wp;
    wp += (bytes + 255) & ~size_t(255);
    return r;
  };
  int*    bincnt = (int*)alloc((size_t)NBIN * 4);
  int*    binptr = (int*)alloc((size_t)(NBIN + 1) * 4);
  int*    cursor = (int*)alloc((size_t)NBIN * 4);
  int*    bedge  = (int*)alloc((size_t)NE * 4);
  int*    csr    = (int*)alloc((size_t)(NE + (size_t)NBIN * BSTRIDE + 64) * 4);  // padded CSR
  int*    rowptr = (int*)alloc((size_t)NN * 4);
  int*    deg    = (int*)alloc((size_t)NN * 4);
  float*  dinv   = (float*)alloc((size_t)NN * 4);
  float*  xs     = (float*)alloc((size_t)NN * 2 * 4);
  __half* h1s    = (__half*)alloc((size_t)(NN + 1) * HID * 2);  // fp16, +1 zero pad row
  float*  ps     = (float*)alloc((size_t)NN * 4);

  hipMemsetAsync(bincnt, 0, (size_t)NBIN * 4, stream);
  hipMemsetAsync(h1s + (size_t)NN * HID, 0, HID * 2, stream);  // zero pad row
  k_binhist  <<<NB, 256, 0, stream>>>(ei, bincnt);
  k_binscan  <<<1, 1024, 0, stream>>>(bincnt, binptr, cursor);
  k_wcscatter<<<NCHUNK * NPART, 256, 0, stream>>>(ei, cursor, bedge);
  k_sort     <<<NBIN, 256, 0, stream>>>(binptr, bedge, x, csr, rowptr, deg, dinv, xs);
  k_l1       <<<NB, 256, 0, stream>>>(rowptr, deg, csr, dinv, xs, w1, b1, g1, be1, h1s);
  k_l2       <<<NN / 8, 256, 0, stream>>>(rowptr, deg, csr, dinv, h1s,
                                          w2, b2, g2, be2, w3, ps);
  k_l3       <<<NB, 256, 0, stream>>>(rowptr, deg, csr, dinv, ps, b3, out);
}